// Round 1
// baseline (642.887 us; speedup 1.0000x reference)
//
#include <hip/hip_runtime.h>

// out[b,j,p] = sum_d x[b, nfj[j], d] * W[j,p,d] + bias[j,p]
// B=16384, N=32, D=256, J=23, P=2. Memory-bound: ~386 MB x-read is the floor.

constexpr int Bn = 16384;
constexpr int Nn = 32;
constexpr int Dn = 256;
constexpr int Jn = 23;
constexpr int Pn = 2;

// 4 (b,j) pairs per wave; 16 lanes per pair; each lane handles 16 floats of D.
__global__ __launch_bounds__(256) void detok_kernel(
    const float* __restrict__ x, const float* __restrict__ W,
    const float* __restrict__ bias, const int* __restrict__ nfj,
    float* __restrict__ out)
{
    const int tid   = blockIdx.x * blockDim.x + threadIdx.x;
    const int wave  = tid >> 6;
    const int lane  = threadIdx.x & 63;
    const int group = lane >> 4;   // 0..3: which (b,j) pair in this wave
    const int gl    = lane & 15;   // 0..15: lane within group

    const int pair = wave * 4 + group;      // flat (b,j) index; grid is exact
    const int b = pair / Jn;
    const int j = pair - b * Jn;
    const int node = nfj[j];

    const float4* __restrict__ xr =
        reinterpret_cast<const float4*>(x + ((size_t)b * Nn + node) * Dn);
    const float4* __restrict__ w0 =
        reinterpret_cast<const float4*>(W + ((size_t)j * Pn + 0) * Dn);
    const float4* __restrict__ w1 =
        reinterpret_cast<const float4*>(W + ((size_t)j * Pn + 1) * Dn);

    float s0 = 0.f, s1 = 0.f;
#pragma unroll
    for (int k = 0; k < 4; ++k) {
        const int idx = k * 16 + gl;        // float4 index within the 256-float row
        float4 xv = xr[idx];
        float4 a0 = w0[idx];
        float4 a1 = w1[idx];
        s0 += xv.x * a0.x + xv.y * a0.y + xv.z * a0.z + xv.w * a0.w;
        s1 += xv.x * a1.x + xv.y * a1.y + xv.z * a1.z + xv.w * a1.w;
    }

    // reduce across the 16-lane group (xor masks 1,2,4,8 stay inside the group)
#pragma unroll
    for (int off = 8; off >= 1; off >>= 1) {
        s0 += __shfl_xor(s0, off, 64);
        s1 += __shfl_xor(s1, off, 64);
    }

    if (gl == 0) {
        float2 bj = *reinterpret_cast<const float2*>(bias + j * Pn);
        float2 o;
        o.x = s0 + bj.x;
        o.y = s1 + bj.y;
        *reinterpret_cast<float2*>(out + (size_t)pair * Pn) = o;
    }
}

extern "C" void kernel_launch(void* const* d_in, const int* in_sizes, int n_in,
                              void* d_out, int out_size, void* d_ws, size_t ws_size,
                              hipStream_t stream) {
    const float* x    = (const float*)d_in[0];
    const float* W    = (const float*)d_in[1];
    const float* bias = (const float*)d_in[2];
    const int*   nfj  = (const int*)d_in[3];
    float* out = (float*)d_out;

    const int total_pairs = Bn * Jn;             // 376832
    const int pairs_per_block = (256 / 64) * 4;  // 16
    const int grid = total_pairs / pairs_per_block;  // 23552, exact

    detok_kernel<<<grid, 256, 0, stream>>>(x, W, bias, nfj, out);
}